// Round 8
// baseline (191.407 us; speedup 1.0000x reference)
//
#include <hip/hip_runtime.h>
#include <hip/hip_bf16.h>
#include <cstdint>

// ---------------------------------------------------------------------------
// SAGE GNN, 2 layers, N=50000, E=800000, D: 128 -> 256 -> 128.
// csr_kernel (ONE 98-block kernel, device-scope barriers, all co-resident):
//   ph1 hist -> blockhist[pb][1024]        (LDS hist, plain stores)
//   ph2 column scan (wave shfl-scan over 98 blocks per bucket) -> prefix+btot
//   ph3 bucket exclusive scan (block 0) -> brow
//   ph4 bin: cursors = brow + own prefix -> bucket-sorted stage (packed 4B)
//   ph5 scatter: 8 buckets/block, per-node deg+scan in LDS -> rowptr, col(u16)
// Dense path:
//   prep: BT1/BT2 bf16^T weights + A1[:,128:256] = bf16(x)
//   agg1: A1[:,0:128] = mean_in(bf16 x)          (wave/node, 8-deep unroll)
//   gemm_fused: h = relu(A1@W1+b1) -> LDS (swizzled); hw2 = h@[W2l|W2r]
//   agg2: out = mean_in(hw2[:,:128]) + hw2[:,128:] + b2
// ---------------------------------------------------------------------------

static inline size_t align_up(size_t x, size_t a) { return (x + a - 1) & ~(a - 1); }

using short8 = __attribute__((ext_vector_type(8))) short;
using f32x4  = __attribute__((ext_vector_type(4))) float;

#define BSHIFT 6   // 64 nodes per bucket; NB = ceil(N/64) = 782 (<= 1024)
#define PB 98      // blocks in csr_kernel; must be <= CU count (co-residency)

__device__ __forceinline__ float bfpair_lo(unsigned int v) {
  union { unsigned int i; float f; } u; u.i = v << 16; return u.f;
}
__device__ __forceinline__ float bfpair_hi(unsigned int v) {
  union { unsigned int i; float f; } u; u.i = v & 0xffff0000u; return u.f;
}
__device__ __forceinline__ unsigned short f2bf(float f) {
  union { float f; unsigned int i; } u; u.f = f;
  unsigned int r = u.i + 0x7fffu + ((u.i >> 16) & 1u);
  return (unsigned short)(r >> 16);
}

__device__ __forceinline__ void gload_lds16(const void* g, void* l) {
  __builtin_amdgcn_global_load_lds(
      (const __attribute__((address_space(1))) void*)g,
      (__attribute__((address_space(3))) void*)l, 16, 0, 0);
}

// one-shot grid barrier (slot = 2 ints, pre-zeroed); agent-scope fences
__device__ __forceinline__ void gbar(int* bar, int nblocks) {
  __syncthreads();
  if (threadIdx.x == 0) {
    __builtin_amdgcn_fence(__ATOMIC_RELEASE, "agent");
    int prev = __hip_atomic_fetch_add(&bar[0], 1, __ATOMIC_RELAXED,
                                      __HIP_MEMORY_SCOPE_AGENT);
    if (prev + 1 == nblocks) {
      __hip_atomic_store(&bar[1], 1, __ATOMIC_RELAXED, __HIP_MEMORY_SCOPE_AGENT);
    } else {
      while (!__hip_atomic_load(&bar[1], __ATOMIC_RELAXED,
                                __HIP_MEMORY_SCOPE_AGENT))
        __builtin_amdgcn_s_sleep(2);
    }
    __builtin_amdgcn_fence(__ATOMIC_ACQUIRE, "agent");
  }
  __syncthreads();
}

// ------------------------- fused CSR build ---------------------------------

__global__ __launch_bounds__(256) void csr_kernel(
    const int* __restrict__ src, const int* __restrict__ dst,
    int* __restrict__ blockhist, int* __restrict__ btot,
    int* __restrict__ brow, unsigned* __restrict__ stage,
    int* __restrict__ rowptr, unsigned short* __restrict__ col,
    int* __restrict__ bar, int N, int E, int NB, int chunk) {
  __shared__ int lds_i[1024];
  const int t = threadIdx.x;
  const int pb = blockIdx.x;
  const int e0 = pb * chunk;
  const int e1 = min(e0 + chunk, E);

  // ---- phase 1: per-block bucket histogram ----
  for (int i = t; i < 1024; i += 256) lds_i[i] = 0;
  __syncthreads();
  for (int e = e0 + t; e < e1; e += 256) atomicAdd(&lds_i[dst[e] >> BSHIFT], 1);
  __syncthreads();
  for (int i = t; i < 1024; i += 256) blockhist[pb * 1024 + i] = lds_i[i];
  gbar(bar + 0, PB);

  // ---- phase 2: per-bucket scan over the 98 blocks (wave shfl-scan) ----
  {
    const int lane = t & 63, w = t >> 6;
    for (int r = 0;; ++r) {
      const int idx = w + 4 * r;            // 0..10
      if (idx >= 11) break;
      const int i = pb + PB * idx;          // unique bucket
      if (i >= 1024) break;
      int v0 = blockhist[lane * 1024 + i];
      int v1 = (64 + lane < PB) ? blockhist[(64 + lane) * 1024 + i] : 0;
      int s0 = v0, s1 = v1;
      #pragma unroll
      for (int off = 1; off < 64; off <<= 1) {
        int u0 = __shfl_up(s0, off, 64);
        int u1 = __shfl_up(s1, off, 64);
        if (lane >= off) { s0 += u0; s1 += u1; }
      }
      int T0 = __shfl(s0, 63, 64);
      blockhist[lane * 1024 + i] = s0 - v0;
      if (64 + lane < PB) blockhist[(64 + lane) * 1024 + i] = T0 + s1 - v1;
      if (lane == 63) btot[i] = T0 + s1;
    }
  }
  gbar(bar + 2, PB);

  // ---- phase 3: exclusive scan of 1024 bucket totals (block 0) ----
  if (pb == 0) {
    int4 v = *reinterpret_cast<const int4*>(btot + t * 4);
    int tsum = v.x + v.y + v.z + v.w;
    const int lane = t & 63, w = t >> 6;
    int inc = tsum;
    #pragma unroll
    for (int off = 1; off < 64; off <<= 1) {
      int u = __shfl_up(inc, off, 64);
      if (lane >= off) inc += u;
    }
    if (lane == 63) lds_i[w] = inc;  // wsum
    __syncthreads();
    int woff = 0;
    for (int k = 0; k < w; ++k) woff += lds_i[k];
    int e0x = woff + inc - tsum;
    const int base = t * 4;
    int p0 = e0x, p1 = p0 + v.x, p2 = p1 + v.y, p3 = p2 + v.z;
    if (base + 0 < NB) brow[base + 0] = p0;
    if (base + 1 < NB) brow[base + 1] = p1;
    if (base + 2 < NB) brow[base + 2] = p2;
    if (base + 3 < NB) brow[base + 3] = p3;
    __syncthreads();
    if (t == 0) brow[NB] = lds_i[0] + lds_i[1] + lds_i[2] + lds_i[3];
  }
  gbar(bar + 4, PB);

  // ---- phase 4: bin edges (cursors = brow + own prefix; LDS atomics) ----
  for (int i = t; i < 1024; i += 256)
    lds_i[i] = (i < NB) ? (brow[i] + blockhist[pb * 1024 + i]) : 0;
  __syncthreads();
  for (int e = e0 + t; e < e1; e += 256) {
    int d = dst[e];
    int p = atomicAdd(&lds_i[d >> BSHIFT], 1);
    stage[p] = (unsigned)src[e] | ((unsigned)(d & 63) << 16);
  }
  gbar(bar + 6, PB);

  // ---- phase 5: per-bucket scatter (8 buckets per block) ----
  if (pb == 0 && t == 0) rowptr[N] = E;
  int* dcnt = lds_i;
  int* dbase = lds_i + 64;
  const int bbe = min(pb * 8 + 8, NB);
  for (int bb = pb * 8; bb < bbe; ++bb) {
    const int n0 = bb << BSHIFT;
    const int lo = brow[bb], hi = brow[bb + 1];
    __syncthreads();
    if (t < 64) dcnt[t] = 0;
    __syncthreads();
    for (int e = lo + t; e < hi; e += 256) atomicAdd(&dcnt[stage[e] >> 16], 1);
    __syncthreads();
    if (t < 64) {
      int v = dcnt[t];
      int inc = v;
      #pragma unroll
      for (int off = 1; off < 64; off <<= 1) {
        int u = __shfl_up(inc, off, 64);
        if (t >= off) inc += u;
      }
      int excl = lo + inc - v;
      dbase[t] = excl;
      dcnt[t] = 0;  // reuse as cursor
      if (n0 + t < N) rowptr[n0 + t] = excl;
    }
    __syncthreads();
    for (int e = lo + t; e < hi; e += 256) {
      unsigned pr = stage[e];
      int d = pr >> 16;
      int p = atomicAdd(&dcnt[d], 1);
      col[dbase[d] + p] = (unsigned short)(pr & 0xffffu);
    }
  }
}

// --------------------- prep: weights (bf16^T) + x convert ------------------
__global__ __launch_bounds__(256) void prep_kernel(
    const float* __restrict__ x,
    const float* __restrict__ W1l, const float* __restrict__ W1r,
    const float* __restrict__ W2l, const float* __restrict__ W2r,
    __hip_bfloat16* __restrict__ BT1, __hip_bfloat16* __restrict__ BT2,
    __hip_bfloat16* __restrict__ A1, int total4) {
  const int bb = blockIdx.x;
  const int t = threadIdx.x;
  if (bb < 512) {
    int idx = (bb & 255) * 256 + t;
    int n = idx >> 8, k = idx & 255;
    if (bb < 256) {
      float v = (k < 128) ? W1l[k * 256 + n] : W1r[(k - 128) * 256 + n];
      BT1[idx] = __float2bfloat16(v);
    } else {
      float v = (n < 128) ? W2l[k * 128 + n] : W2r[k * 128 + (n - 128)];
      BT2[idx] = __float2bfloat16(v);
    }
    return;
  }
  int idx = (bb - 512) * 256 + t;
  if (idx >= total4) return;
  int i = idx >> 5, j4 = (idx & 31) << 2;
  float4 v = *reinterpret_cast<const float4*>(x + (size_t)i * 128 + j4);
  unsigned p0 = ((unsigned)f2bf(v.y) << 16) | f2bf(v.x);
  unsigned p1 = ((unsigned)f2bf(v.w) << 16) | f2bf(v.z);
  *reinterpret_cast<uint2*>(A1 + (size_t)i * 256 + 128 + j4) = make_uint2(p0, p1);
}

// ------------------------------ aggregations -------------------------------
// one wave per node; 8-edge unrolled gathers (8 x 256B rows in flight/wave)

__global__ __launch_bounds__(64) void agg1_kernel(const int* __restrict__ rowptr,
                                                  const unsigned short* __restrict__ col,
                                                  __hip_bfloat16* __restrict__ A1) {
  const int i = blockIdx.x;
  const int t = threadIdx.x;  // 0..63
  const int beg = rowptr[i], end = rowptr[i + 1];
  float ax = 0.f, ay = 0.f;
  int e = beg;
  for (; e + 7 < end; e += 8) {
    unsigned v0 = *reinterpret_cast<const unsigned*>(A1 + (size_t)col[e]     * 256 + 128 + t * 2);
    unsigned v1 = *reinterpret_cast<const unsigned*>(A1 + (size_t)col[e + 1] * 256 + 128 + t * 2);
    unsigned v2 = *reinterpret_cast<const unsigned*>(A1 + (size_t)col[e + 2] * 256 + 128 + t * 2);
    unsigned v3 = *reinterpret_cast<const unsigned*>(A1 + (size_t)col[e + 3] * 256 + 128 + t * 2);
    unsigned v4 = *reinterpret_cast<const unsigned*>(A1 + (size_t)col[e + 4] * 256 + 128 + t * 2);
    unsigned v5 = *reinterpret_cast<const unsigned*>(A1 + (size_t)col[e + 5] * 256 + 128 + t * 2);
    unsigned v6 = *reinterpret_cast<const unsigned*>(A1 + (size_t)col[e + 6] * 256 + 128 + t * 2);
    unsigned v7 = *reinterpret_cast<const unsigned*>(A1 + (size_t)col[e + 7] * 256 + 128 + t * 2);
    ax += ((bfpair_lo(v0) + bfpair_lo(v1)) + (bfpair_lo(v2) + bfpair_lo(v3))) +
          ((bfpair_lo(v4) + bfpair_lo(v5)) + (bfpair_lo(v6) + bfpair_lo(v7)));
    ay += ((bfpair_hi(v0) + bfpair_hi(v1)) + (bfpair_hi(v2) + bfpair_hi(v3))) +
          ((bfpair_hi(v4) + bfpair_hi(v5)) + (bfpair_hi(v6) + bfpair_hi(v7)));
  }
  for (; e + 1 < end; e += 2) {
    unsigned v0 = *reinterpret_cast<const unsigned*>(A1 + (size_t)col[e]     * 256 + 128 + t * 2);
    unsigned v1 = *reinterpret_cast<const unsigned*>(A1 + (size_t)col[e + 1] * 256 + 128 + t * 2);
    ax += bfpair_lo(v0) + bfpair_lo(v1);
    ay += bfpair_hi(v0) + bfpair_hi(v1);
  }
  if (e < end) {
    unsigned v0 = *reinterpret_cast<const unsigned*>(A1 + (size_t)col[e] * 256 + 128 + t * 2);
    ax += bfpair_lo(v0);
    ay += bfpair_hi(v0);
  }
  int d = end - beg;
  float inv = 1.0f / (float)(d > 1 ? d : 1);
  unsigned pk = ((unsigned)f2bf(ay * inv) << 16) | f2bf(ax * inv);
  *reinterpret_cast<unsigned*>(A1 + (size_t)i * 256 + t * 2) = pk;
}

__global__ __launch_bounds__(64) void agg2_kernel(const __hip_bfloat16* __restrict__ hw2,
                                                  const int* __restrict__ rowptr,
                                                  const unsigned short* __restrict__ col,
                                                  const float* __restrict__ b2,
                                                  float* __restrict__ out) {
  const int i = blockIdx.x;
  const int t = threadIdx.x;  // 0..63
  const int beg = rowptr[i], end = rowptr[i + 1];
  float ax = 0.f, ay = 0.f;
  int e = beg;
  for (; e + 7 < end; e += 8) {
    unsigned v0 = *reinterpret_cast<const unsigned*>(hw2 + (size_t)col[e]     * 256 + t * 2);
    unsigned v1 = *reinterpret_cast<const unsigned*>(hw2 + (size_t)col[e + 1] * 256 + t * 2);
    unsigned v2 = *reinterpret_cast<const unsigned*>(hw2 + (size_t)col[e + 2] * 256 + t * 2);
    unsigned v3 = *reinterpret_cast<const unsigned*>(hw2 + (size_t)col[e + 3] * 256 + t * 2);
    unsigned v4 = *reinterpret_cast<const unsigned*>(hw2 + (size_t)col[e + 4] * 256 + t * 2);
    unsigned v5 = *reinterpret_cast<const unsigned*>(hw2 + (size_t)col[e + 5] * 256 + t * 2);
    unsigned v6 = *reinterpret_cast<const unsigned*>(hw2 + (size_t)col[e + 6] * 256 + t * 2);
    unsigned v7 = *reinterpret_cast<const unsigned*>(hw2 + (size_t)col[e + 7] * 256 + t * 2);
    ax += ((bfpair_lo(v0) + bfpair_lo(v1)) + (bfpair_lo(v2) + bfpair_lo(v3))) +
          ((bfpair_lo(v4) + bfpair_lo(v5)) + (bfpair_lo(v6) + bfpair_lo(v7)));
    ay += ((bfpair_hi(v0) + bfpair_hi(v1)) + (bfpair_hi(v2) + bfpair_hi(v3))) +
          ((bfpair_hi(v4) + bfpair_hi(v5)) + (bfpair_hi(v6) + bfpair_hi(v7)));
  }
  for (; e + 1 < end; e += 2) {
    unsigned v0 = *reinterpret_cast<const unsigned*>(hw2 + (size_t)col[e]     * 256 + t * 2);
    unsigned v1 = *reinterpret_cast<const unsigned*>(hw2 + (size_t)col[e + 1] * 256 + t * 2);
    ax += bfpair_lo(v0) + bfpair_lo(v1);
    ay += bfpair_hi(v0) + bfpair_hi(v1);
  }
  if (e < end) {
    unsigned v0 = *reinterpret_cast<const unsigned*>(hw2 + (size_t)col[e] * 256 + t * 2);
    ax += bfpair_lo(v0);
    ay += bfpair_hi(v0);
  }
  int d = end - beg;
  float inv = 1.0f / (float)(d > 1 ? d : 1);
  unsigned sv = *reinterpret_cast<const unsigned*>(hw2 + (size_t)i * 256 + 128 + t * 2);
  float2 bb = *reinterpret_cast<const float2*>(b2 + t * 2);
  float2 r;
  r.x = ax * inv + bfpair_lo(sv) + bb.x;
  r.y = ay * inv + bfpair_hi(sv) + bb.y;
  *reinterpret_cast<float2*>(out + (size_t)i * 128 + t * 2) = r;
}

// --------------------------- FUSED double GEMM -----------------------------
__global__ __launch_bounds__(256) void gemm_fused_kernel(
    const __hip_bfloat16* __restrict__ A1,   // [M][256]
    const __hip_bfloat16* __restrict__ BT1,  // [256][256] = B1^T
    const __hip_bfloat16* __restrict__ BT2,  // [256][256] = B2^T
    const float* __restrict__ b1,            // [256]
    __hip_bfloat16* __restrict__ hw2,        // [M][256]
    int M) {
  __shared__ __hip_bfloat16 As[64 * 32];        // 4 KB
  __shared__ __hip_bfloat16 Bs[256 * 32];       // 16 KB
  __shared__ __hip_bfloat16 hLds[64 * 256];     // 32 KB, swizzled
  const int t = threadIdx.x;
  const int lane = t & 63;
  const int w = t >> 6;
  const int wc = w * 64;
  const int bm = blockIdx.x * 64;

  const int srow4 = lane >> 2;
  const int sbyte = (lane & 3) * 16;
  const int fr = lane & 15;
  const int fbyte = (lane >> 4) * 16;
  const int kslot = lane >> 4;

  f32x4 acc[4][4];
  #pragma unroll
  for (int i = 0; i < 4; ++i)
    #pragma unroll
    for (int j = 0; j < 4; ++j) acc[i][j] = (f32x4)(0.f);

  // phase 1: h = relu(A1 @ BT1^T + b1)
  for (int k0 = 0; k0 < 256; k0 += 32) {
    {
      int gr = bm + w * 16 + srow4;
      if (gr >= M) gr = M - 1;
      gload_lds16((const char*)A1 + (size_t)gr * 512 + k0 * 2 + sbyte,
                  (char*)As + w * 1024);
    }
    #pragma unroll
    for (int q = 0; q < 4; ++q) {
      const int c = w * 4 + q;
      const int row = c * 16 + srow4;
      gload_lds16((const char*)BT1 + (size_t)row * 512 + k0 * 2 + sbyte,
                  (char*)Bs + c * 1024);
    }
    __syncthreads();
    short8 af[4], bf[4];
    #pragma unroll
    for (int i = 0; i < 4; ++i) {
      af[i] = *reinterpret_cast<const short8*>((const char*)As + (fr + i * 16) * 64 + fbyte);
      bf[i] = *reinterpret_cast<const short8*>((const char*)Bs + (wc + fr + i * 16) * 64 + fbyte);
    }
    #pragma unroll
    for (int i = 0; i < 4; ++i)
      #pragma unroll
      for (int j = 0; j < 4; ++j)
        acc[i][j] = __builtin_amdgcn_mfma_f32_16x16x32_bf16(af[i], bf[j], acc[i][j], 0, 0, 0);
    __syncthreads();
  }

  // epilogue 1: bias + relu -> hLds (swizzled)
  {
    const int c0 = wc + fr;
    const int r0 = (lane >> 4) * 4;
    float bj[4];
    #pragma unroll
    for (int j = 0; j < 4; ++j) bj[j] = b1[c0 + j * 16];
    #pragma unroll
    for (int i = 0; i < 4; ++i) {
      #pragma unroll
      for (int j = 0; j < 4; ++j) {
        const int c = c0 + j * 16;
        #pragma unroll
        for (int q = 0; q < 4; ++q) {
          const int r = r0 + i * 16 + q;
          float v = fmaxf(acc[i][j][q] + bj[j], 0.f);
          const int byte = r * 512 + (((c >> 3) ^ (r & 7)) << 4) + ((c & 7) << 1);
          *reinterpret_cast<__hip_bfloat16*>((char*)hLds + byte) = __float2bfloat16(v);
        }
      }
    }
  }

  // phase 2: hw2 = h @ BT2^T
  #pragma unroll
  for (int i = 0; i < 4; ++i)
    #pragma unroll
    for (int j = 0; j < 4; ++j) acc[i][j] = (f32x4)(0.f);

  for (int k0 = 0; k0 < 256; k0 += 32) {
    #pragma unroll
    for (int q = 0; q < 4; ++q) {
      const int c = w * 4 + q;
      const int row = c * 16 + srow4;
      gload_lds16((const char*)BT2 + (size_t)row * 512 + k0 * 2 + sbyte,
                  (char*)Bs + c * 1024);
    }
    __syncthreads();
    short8 af[4], bf[4];
    const int ks = (k0 >> 3) + kslot;
    #pragma unroll
    for (int i = 0; i < 4; ++i) {
      const int ra = fr + i * 16;
      af[i] = *reinterpret_cast<const short8*>(
          (const char*)hLds + ra * 512 + ((ks ^ (ra & 7)) << 4));
      bf[i] = *reinterpret_cast<const short8*>((const char*)Bs + (wc + fr + i * 16) * 64 + fbyte);
    }
    #pragma unroll
    for (int i = 0; i < 4; ++i)
      #pragma unroll
      for (int j = 0; j < 4; ++j)
        acc[i][j] = __builtin_amdgcn_mfma_f32_16x16x32_bf16(af[i], bf[j], acc[i][j], 0, 0, 0);
    __syncthreads();
  }

  // epilogue 2
  {
    const int c0 = wc + fr;
    const int r0 = (lane >> 4) * 4;
    #pragma unroll
    for (int i = 0; i < 4; ++i) {
      #pragma unroll
      for (int q = 0; q < 4; ++q) {
        const int r = bm + r0 + i * 16 + q;
        if (r < M) {
          #pragma unroll
          for (int j = 0; j < 4; ++j)
            hw2[(size_t)r * 256 + c0 + j * 16] = __float2bfloat16(acc[i][j][q]);
        }
      }
    }
  }
}

// ------------------------------ launcher -----------------------------------

extern "C" void kernel_launch(void* const* d_in, const int* in_sizes, int n_in,
                              void* d_out, int out_size, void* d_ws, size_t ws_size,
                              hipStream_t stream) {
  const float* x    = (const float*)d_in[0];
  const int*   edge = (const int*)d_in[1];
  const float* W1_l = (const float*)d_in[2];
  const float* b1   = (const float*)d_in[3];
  const float* W1_r = (const float*)d_in[4];
  const float* W2_l = (const float*)d_in[5];
  const float* b2   = (const float*)d_in[6];
  const float* W2_r = (const float*)d_in[7];
  float* out = (float*)d_out;

  const int N = in_sizes[0] / 128;  // 50000 (packing assumes N <= 65536)
  const int E = in_sizes[1] / 2;
  const int* srcv = edge;
  const int* dstv = edge + E;
  const int NB = (N + (1 << BSHIFT) - 1) >> BSHIFT;  // 782 (<= PB*8 = 784)

  char* ws = (char*)d_ws;
  size_t off = 0;
  auto alloc = [&](size_t bytes) -> void* {
    void* p = ws + off;
    off += align_up(bytes, 256);
    return p;
  };
  int* bar       = (int*)alloc(64);
  int* rowptr    = (int*)alloc((size_t)(N + 1) * 4);
  int* brow      = (int*)alloc((size_t)(NB + 1) * 4);
  int* btot      = (int*)alloc(1024 * 4);
  int* blockhist = (int*)alloc((size_t)PB * 1024 * 4);
  unsigned short* col = (unsigned short*)alloc((size_t)E * 2);
  unsigned* stage = (unsigned*)alloc((size_t)E * 4);
  __hip_bfloat16* BT1 = (__hip_bfloat16*)alloc(256 * 256 * 2);
  __hip_bfloat16* BT2 = (__hip_bfloat16*)alloc(256 * 256 * 2);
  __hip_bfloat16* A1  = (__hip_bfloat16*)alloc((size_t)N * 256 * 2);
  __hip_bfloat16* hw2 = (__hip_bfloat16*)alloc((size_t)N * 256 * 2);

  hipMemsetAsync(bar, 0, 64, stream);

  const int conv_blocks = (N * 32 + 255) / 256;
  prep_kernel<<<512 + conv_blocks, 256, 0, stream>>>(x, W1_l, W1_r, W2_l, W2_r,
                                                     BT1, BT2, A1, N * 32);

  const int chunk = (E + PB - 1) / PB;
  csr_kernel<<<PB, 256, 0, stream>>>(srcv, dstv, blockhist, btot, brow, stage,
                                     rowptr, col, bar, N, E, NB, chunk);

  agg1_kernel<<<N, 64, 0, stream>>>(rowptr, col, A1);

  gemm_fused_kernel<<<(N + 63) / 64, 256, 0, stream>>>(A1, BT1, BT2, b1, hw2, N);

  agg2_kernel<<<N, 64, 0, stream>>>(hw2, rowptr, col, b2, out);
}

// Round 9
// 154.766 us; speedup vs baseline: 1.2368x; 1.2368x over previous
//
#include <hip/hip_runtime.h>
#include <hip/hip_bf16.h>
#include <cstdint>

// ---------------------------------------------------------------------------
// SAGE GNN, 2 layers, N=50000, E=800000, D: 128 -> 256 -> 128.
// CSR build (atomic-free at global scope, 4 small kernels — the fused
// persistent-kernel variant measured 3x slower at 4% occupancy, reverted):
//   bhist -> blockhist[pb][1024];  scan_all (1 block: column scan + bucket
//   exclusive scan) -> brow;  bin2 (cursors = brow + own prefix) -> stage;
//   scatter2b -> rowptr, col(u16).
// Dense path:
//   prep: BT1/BT2 bf16^T weights + A1[:,128:256] = bf16(x)
//   agg1: A1[:,0:128] = mean_in(bf16 x)       (wave/node, 8-deep unroll)
//   gemm_fused: h = relu(A1@W1+b1) -> LDS (swizzled); hw2 = h@[W2l|W2r]
//   agg2: out = mean_in(hw2[:,:128]) + hw2[:,128:] + b2
// ---------------------------------------------------------------------------

static inline size_t align_up(size_t x, size_t a) { return (x + a - 1) & ~(a - 1); }

using short8 = __attribute__((ext_vector_type(8))) short;
using f32x4  = __attribute__((ext_vector_type(4))) float;

#define BSHIFT 6   // 64 nodes per bucket; NB = ceil(N/64) = 782 (<= 1024)
#define PB 98      // partition blocks for hist/bin

__device__ __forceinline__ float bfpair_lo(unsigned int v) {
  union { unsigned int i; float f; } u; u.i = v << 16; return u.f;
}
__device__ __forceinline__ float bfpair_hi(unsigned int v) {
  union { unsigned int i; float f; } u; u.i = v & 0xffff0000u; return u.f;
}
__device__ __forceinline__ unsigned short f2bf(float f) {
  union { float f; unsigned int i; } u; u.f = f;
  unsigned int r = u.i + 0x7fffu + ((u.i >> 16) & 1u);
  return (unsigned short)(r >> 16);
}

__device__ __forceinline__ void gload_lds16(const void* g, void* l) {
  __builtin_amdgcn_global_load_lds(
      (const __attribute__((address_space(1))) void*)g,
      (__attribute__((address_space(3))) void*)l, 16, 0, 0);
}

// ------------------------------- CSR build ---------------------------------

__global__ __launch_bounds__(256) void bhist_kernel(const int* __restrict__ dst,
                                                    int* __restrict__ blockhist,
                                                    int E, int chunk) {
  __shared__ int h[1024];
  const int t = threadIdx.x;
  const int pb = blockIdx.x;
  #pragma unroll
  for (int i = t; i < 1024; i += 256) h[i] = 0;
  __syncthreads();
  const int e0 = pb * chunk;
  int e1 = e0 + chunk; if (e1 > E) e1 = E;
  for (int e = e0 + t; e < e1; e += 256) atomicAdd(&h[dst[e] >> BSHIFT], 1);
  __syncthreads();
  #pragma unroll
  for (int i = t; i < 1024; i += 256) blockhist[pb * 1024 + i] = h[i];
}

// ONE block, 1024 threads: per-bucket serial scan over PB blocks (in place)
// + block-wide exclusive scan of bucket totals -> brow[0..NB]
__global__ __launch_bounds__(1024) void scan_all_kernel(int* __restrict__ blockhist,
                                                        int* __restrict__ brow, int NB) {
  const int i = threadIdx.x;  // 0..1023 = bucket id
  int run = 0;
  for (int pb = 0; pb < PB; ++pb) {
    int v = blockhist[pb * 1024 + i];
    blockhist[pb * 1024 + i] = run;
    run += v;
  }
  const int lane = i & 63, w = i >> 6;  // 16 waves
  int inc = run;
  #pragma unroll
  for (int off = 1; off < 64; off <<= 1) {
    int u = __shfl_up(inc, off, 64);
    if (lane >= off) inc += u;
  }
  __shared__ int wsum[16];
  if (lane == 63) wsum[w] = inc;
  __syncthreads();
  int woff = 0;
  for (int k = 0; k < w; ++k) woff += wsum[k];
  int excl = woff + inc - run;
  if (i < NB) brow[i] = excl;
  if (i == 1023) brow[NB] = woff + inc;  // grand total (tail buckets are 0)
}

// cursors = brow + own prefix (no global atomics); place packed 4B entries
__global__ __launch_bounds__(256) void bin2_kernel(const int* __restrict__ src,
                                                   const int* __restrict__ dst,
                                                   const int* __restrict__ brow,
                                                   const int* __restrict__ blockhist,
                                                   unsigned* __restrict__ stage,
                                                   int E, int NB, int chunk) {
  __shared__ int cur[1024];
  const int t = threadIdx.x;
  const int pb = blockIdx.x;
  for (int i = t; i < 1024; i += 256)
    cur[i] = (i < NB) ? (brow[i] + blockhist[pb * 1024 + i]) : 0;
  __syncthreads();
  const int e0 = pb * chunk;
  int e1 = e0 + chunk; if (e1 > E) e1 = E;
  for (int e = e0 + t; e < e1; e += 256) {
    int d = dst[e];
    int p = atomicAdd(&cur[d >> BSHIFT], 1);
    stage[p] = (unsigned)src[e] | ((unsigned)(d & 63) << 16);
  }
}

// one block per bucket: node-local deg count + scan in LDS -> rowptr, col(u16)
__global__ __launch_bounds__(256) void scatter2b_kernel(const unsigned* __restrict__ stage,
                                                        const int* __restrict__ brow,
                                                        int* __restrict__ rowptr,
                                                        unsigned short* __restrict__ col,
                                                        int N, int E) {
  __shared__ int dcnt[64];
  __shared__ int dbase[64];
  const int b = blockIdx.x;
  const int t = threadIdx.x;
  const int n0 = b << BSHIFT;
  const int lo = brow[b], hi = brow[b + 1];
  if (t < 64) dcnt[t] = 0;
  __syncthreads();
  for (int e = lo + t; e < hi; e += 256) atomicAdd(&dcnt[stage[e] >> 16], 1);
  __syncthreads();
  if (t < 64) {
    int v = dcnt[t];
    int inc = v;
    #pragma unroll
    for (int off = 1; off < 64; off <<= 1) {
      int u = __shfl_up(inc, off, 64);
      if (t >= off) inc += u;
    }
    int excl = lo + inc - v;
    dbase[t] = excl;
    dcnt[t] = 0;  // reuse as cursor
    if (n0 + t < N) rowptr[n0 + t] = excl;
  }
  if (b == 0 && t == 0) rowptr[N] = E;
  __syncthreads();
  for (int e = lo + t; e < hi; e += 256) {
    unsigned pr = stage[e];
    int d = pr >> 16;
    int p = atomicAdd(&dcnt[d], 1);
    col[dbase[d] + p] = (unsigned short)(pr & 0xffffu);
  }
}

// --------------------- prep: weights (bf16^T) + x convert ------------------
__global__ __launch_bounds__(256) void prep_kernel(
    const float* __restrict__ x,
    const float* __restrict__ W1l, const float* __restrict__ W1r,
    const float* __restrict__ W2l, const float* __restrict__ W2r,
    __hip_bfloat16* __restrict__ BT1, __hip_bfloat16* __restrict__ BT2,
    __hip_bfloat16* __restrict__ A1, int total4) {
  const int bb = blockIdx.x;
  const int t = threadIdx.x;
  if (bb < 512) {
    int idx = (bb & 255) * 256 + t;
    int n = idx >> 8, k = idx & 255;
    if (bb < 256) {
      float v = (k < 128) ? W1l[k * 256 + n] : W1r[(k - 128) * 256 + n];
      BT1[idx] = __float2bfloat16(v);
    } else {
      float v = (n < 128) ? W2l[k * 128 + n] : W2r[k * 128 + (n - 128)];
      BT2[idx] = __float2bfloat16(v);
    }
    return;
  }
  int idx = (bb - 512) * 256 + t;
  if (idx >= total4) return;
  int i = idx >> 5, j4 = (idx & 31) << 2;
  float4 v = *reinterpret_cast<const float4*>(x + (size_t)i * 128 + j4);
  unsigned p0 = ((unsigned)f2bf(v.y) << 16) | f2bf(v.x);
  unsigned p1 = ((unsigned)f2bf(v.w) << 16) | f2bf(v.z);
  *reinterpret_cast<uint2*>(A1 + (size_t)i * 256 + 128 + j4) = make_uint2(p0, p1);
}

// ------------------------------ aggregations -------------------------------
// one wave per node; 8-edge unrolled gathers (8 x 256B rows in flight/wave)

__global__ __launch_bounds__(64) void agg1_kernel(const int* __restrict__ rowptr,
                                                  const unsigned short* __restrict__ col,
                                                  __hip_bfloat16* __restrict__ A1) {
  const int i = blockIdx.x;
  const int t = threadIdx.x;  // 0..63
  const int beg = rowptr[i], end = rowptr[i + 1];
  float ax = 0.f, ay = 0.f;
  int e = beg;
  for (; e + 7 < end; e += 8) {
    unsigned v0 = *reinterpret_cast<const unsigned*>(A1 + (size_t)col[e]     * 256 + 128 + t * 2);
    unsigned v1 = *reinterpret_cast<const unsigned*>(A1 + (size_t)col[e + 1] * 256 + 128 + t * 2);
    unsigned v2 = *reinterpret_cast<const unsigned*>(A1 + (size_t)col[e + 2] * 256 + 128 + t * 2);
    unsigned v3 = *reinterpret_cast<const unsigned*>(A1 + (size_t)col[e + 3] * 256 + 128 + t * 2);
    unsigned v4 = *reinterpret_cast<const unsigned*>(A1 + (size_t)col[e + 4] * 256 + 128 + t * 2);
    unsigned v5 = *reinterpret_cast<const unsigned*>(A1 + (size_t)col[e + 5] * 256 + 128 + t * 2);
    unsigned v6 = *reinterpret_cast<const unsigned*>(A1 + (size_t)col[e + 6] * 256 + 128 + t * 2);
    unsigned v7 = *reinterpret_cast<const unsigned*>(A1 + (size_t)col[e + 7] * 256 + 128 + t * 2);
    ax += ((bfpair_lo(v0) + bfpair_lo(v1)) + (bfpair_lo(v2) + bfpair_lo(v3))) +
          ((bfpair_lo(v4) + bfpair_lo(v5)) + (bfpair_lo(v6) + bfpair_lo(v7)));
    ay += ((bfpair_hi(v0) + bfpair_hi(v1)) + (bfpair_hi(v2) + bfpair_hi(v3))) +
          ((bfpair_hi(v4) + bfpair_hi(v5)) + (bfpair_hi(v6) + bfpair_hi(v7)));
  }
  for (; e + 1 < end; e += 2) {
    unsigned v0 = *reinterpret_cast<const unsigned*>(A1 + (size_t)col[e]     * 256 + 128 + t * 2);
    unsigned v1 = *reinterpret_cast<const unsigned*>(A1 + (size_t)col[e + 1] * 256 + 128 + t * 2);
    ax += bfpair_lo(v0) + bfpair_lo(v1);
    ay += bfpair_hi(v0) + bfpair_hi(v1);
  }
  if (e < end) {
    unsigned v0 = *reinterpret_cast<const unsigned*>(A1 + (size_t)col[e] * 256 + 128 + t * 2);
    ax += bfpair_lo(v0);
    ay += bfpair_hi(v0);
  }
  int d = end - beg;
  float inv = 1.0f / (float)(d > 1 ? d : 1);
  unsigned pk = ((unsigned)f2bf(ay * inv) << 16) | f2bf(ax * inv);
  *reinterpret_cast<unsigned*>(A1 + (size_t)i * 256 + t * 2) = pk;
}

__global__ __launch_bounds__(64) void agg2_kernel(const __hip_bfloat16* __restrict__ hw2,
                                                  const int* __restrict__ rowptr,
                                                  const unsigned short* __restrict__ col,
                                                  const float* __restrict__ b2,
                                                  float* __restrict__ out) {
  const int i = blockIdx.x;
  const int t = threadIdx.x;  // 0..63
  const int beg = rowptr[i], end = rowptr[i + 1];
  float ax = 0.f, ay = 0.f;
  int e = beg;
  for (; e + 7 < end; e += 8) {
    unsigned v0 = *reinterpret_cast<const unsigned*>(hw2 + (size_t)col[e]     * 256 + t * 2);
    unsigned v1 = *reinterpret_cast<const unsigned*>(hw2 + (size_t)col[e + 1] * 256 + t * 2);
    unsigned v2 = *reinterpret_cast<const unsigned*>(hw2 + (size_t)col[e + 2] * 256 + t * 2);
    unsigned v3 = *reinterpret_cast<const unsigned*>(hw2 + (size_t)col[e + 3] * 256 + t * 2);
    unsigned v4 = *reinterpret_cast<const unsigned*>(hw2 + (size_t)col[e + 4] * 256 + t * 2);
    unsigned v5 = *reinterpret_cast<const unsigned*>(hw2 + (size_t)col[e + 5] * 256 + t * 2);
    unsigned v6 = *reinterpret_cast<const unsigned*>(hw2 + (size_t)col[e + 6] * 256 + t * 2);
    unsigned v7 = *reinterpret_cast<const unsigned*>(hw2 + (size_t)col[e + 7] * 256 + t * 2);
    ax += ((bfpair_lo(v0) + bfpair_lo(v1)) + (bfpair_lo(v2) + bfpair_lo(v3))) +
          ((bfpair_lo(v4) + bfpair_lo(v5)) + (bfpair_lo(v6) + bfpair_lo(v7)));
    ay += ((bfpair_hi(v0) + bfpair_hi(v1)) + (bfpair_hi(v2) + bfpair_hi(v3))) +
          ((bfpair_hi(v4) + bfpair_hi(v5)) + (bfpair_hi(v6) + bfpair_hi(v7)));
  }
  for (; e + 1 < end; e += 2) {
    unsigned v0 = *reinterpret_cast<const unsigned*>(hw2 + (size_t)col[e]     * 256 + t * 2);
    unsigned v1 = *reinterpret_cast<const unsigned*>(hw2 + (size_t)col[e + 1] * 256 + t * 2);
    ax += bfpair_lo(v0) + bfpair_lo(v1);
    ay += bfpair_hi(v0) + bfpair_hi(v1);
  }
  if (e < end) {
    unsigned v0 = *reinterpret_cast<const unsigned*>(hw2 + (size_t)col[e] * 256 + t * 2);
    ax += bfpair_lo(v0);
    ay += bfpair_hi(v0);
  }
  int d = end - beg;
  float inv = 1.0f / (float)(d > 1 ? d : 1);
  unsigned sv = *reinterpret_cast<const unsigned*>(hw2 + (size_t)i * 256 + 128 + t * 2);
  float2 bb = *reinterpret_cast<const float2*>(b2 + t * 2);
  float2 r;
  r.x = ax * inv + bfpair_lo(sv) + bb.x;
  r.y = ay * inv + bfpair_hi(sv) + bb.y;
  *reinterpret_cast<float2*>(out + (size_t)i * 128 + t * 2) = r;
}

// --------------------------- FUSED double GEMM -----------------------------
__global__ __launch_bounds__(256) void gemm_fused_kernel(
    const __hip_bfloat16* __restrict__ A1,   // [M][256]
    const __hip_bfloat16* __restrict__ BT1,  // [256][256] = B1^T
    const __hip_bfloat16* __restrict__ BT2,  // [256][256] = B2^T
    const float* __restrict__ b1,            // [256]
    __hip_bfloat16* __restrict__ hw2,        // [M][256]
    int M) {
  __shared__ __hip_bfloat16 As[64 * 32];        // 4 KB
  __shared__ __hip_bfloat16 Bs[256 * 32];       // 16 KB
  __shared__ __hip_bfloat16 hLds[64 * 256];     // 32 KB, swizzled
  const int t = threadIdx.x;
  const int lane = t & 63;
  const int w = t >> 6;
  const int wc = w * 64;
  const int bm = blockIdx.x * 64;

  const int srow4 = lane >> 2;
  const int sbyte = (lane & 3) * 16;
  const int fr = lane & 15;
  const int fbyte = (lane >> 4) * 16;
  const int kslot = lane >> 4;

  f32x4 acc[4][4];
  #pragma unroll
  for (int i = 0; i < 4; ++i)
    #pragma unroll
    for (int j = 0; j < 4; ++j) acc[i][j] = (f32x4)(0.f);

  // phase 1: h = relu(A1 @ BT1^T + b1)
  for (int k0 = 0; k0 < 256; k0 += 32) {
    {
      int gr = bm + w * 16 + srow4;
      if (gr >= M) gr = M - 1;
      gload_lds16((const char*)A1 + (size_t)gr * 512 + k0 * 2 + sbyte,
                  (char*)As + w * 1024);
    }
    #pragma unroll
    for (int q = 0; q < 4; ++q) {
      const int c = w * 4 + q;
      const int row = c * 16 + srow4;
      gload_lds16((const char*)BT1 + (size_t)row * 512 + k0 * 2 + sbyte,
                  (char*)Bs + c * 1024);
    }
    __syncthreads();
    short8 af[4], bf[4];
    #pragma unroll
    for (int i = 0; i < 4; ++i) {
      af[i] = *reinterpret_cast<const short8*>((const char*)As + (fr + i * 16) * 64 + fbyte);
      bf[i] = *reinterpret_cast<const short8*>((const char*)Bs + (wc + fr + i * 16) * 64 + fbyte);
    }
    #pragma unroll
    for (int i = 0; i < 4; ++i)
      #pragma unroll
      for (int j = 0; j < 4; ++j)
        acc[i][j] = __builtin_amdgcn_mfma_f32_16x16x32_bf16(af[i], bf[j], acc[i][j], 0, 0, 0);
    __syncthreads();
  }

  // epilogue 1: bias + relu -> hLds (swizzled)
  {
    const int c0 = wc + fr;
    const int r0 = (lane >> 4) * 4;
    float bj[4];
    #pragma unroll
    for (int j = 0; j < 4; ++j) bj[j] = b1[c0 + j * 16];
    #pragma unroll
    for (int i = 0; i < 4; ++i) {
      #pragma unroll
      for (int j = 0; j < 4; ++j) {
        const int c = c0 + j * 16;
        #pragma unroll
        for (int q = 0; q < 4; ++q) {
          const int r = r0 + i * 16 + q;
          float v = fmaxf(acc[i][j][q] + bj[j], 0.f);
          const int byte = r * 512 + (((c >> 3) ^ (r & 7)) << 4) + ((c & 7) << 1);
          *reinterpret_cast<__hip_bfloat16*>((char*)hLds + byte) = __float2bfloat16(v);
        }
      }
    }
  }

  // phase 2: hw2 = h @ BT2^T
  #pragma unroll
  for (int i = 0; i < 4; ++i)
    #pragma unroll
    for (int j = 0; j < 4; ++j) acc[i][j] = (f32x4)(0.f);

  for (int k0 = 0; k0 < 256; k0 += 32) {
    #pragma unroll
    for (int q = 0; q < 4; ++q) {
      const int c = w * 4 + q;
      const int row = c * 16 + srow4;
      gload_lds16((const char*)BT2 + (size_t)row * 512 + k0 * 2 + sbyte,
                  (char*)Bs + c * 1024);
    }
    __syncthreads();
    short8 af[4], bf[4];
    const int ks = (k0 >> 3) + kslot;
    #pragma unroll
    for (int i = 0; i < 4; ++i) {
      const int ra = fr + i * 16;
      af[i] = *reinterpret_cast<const short8*>(
          (const char*)hLds + ra * 512 + ((ks ^ (ra & 7)) << 4));
      bf[i] = *reinterpret_cast<const short8*>((const char*)Bs + (wc + fr + i * 16) * 64 + fbyte);
    }
    #pragma unroll
    for (int i = 0; i < 4; ++i)
      #pragma unroll
      for (int j = 0; j < 4; ++j)
        acc[i][j] = __builtin_amdgcn_mfma_f32_16x16x32_bf16(af[i], bf[j], acc[i][j], 0, 0, 0);
    __syncthreads();
  }

  // epilogue 2
  {
    const int c0 = wc + fr;
    const int r0 = (lane >> 4) * 4;
    #pragma unroll
    for (int i = 0; i < 4; ++i) {
      #pragma unroll
      for (int q = 0; q < 4; ++q) {
        const int r = bm + r0 + i * 16 + q;
        if (r < M) {
          #pragma unroll
          for (int j = 0; j < 4; ++j)
            hw2[(size_t)r * 256 + c0 + j * 16] = __float2bfloat16(acc[i][j][q]);
        }
      }
    }
  }
}

// ------------------------------ launcher -----------------------------------

extern "C" void kernel_launch(void* const* d_in, const int* in_sizes, int n_in,
                              void* d_out, int out_size, void* d_ws, size_t ws_size,
                              hipStream_t stream) {
  const float* x    = (const float*)d_in[0];
  const int*   edge = (const int*)d_in[1];
  const float* W1_l = (const float*)d_in[2];
  const float* b1   = (const float*)d_in[3];
  const float* W1_r = (const float*)d_in[4];
  const float* W2_l = (const float*)d_in[5];
  const float* b2   = (const float*)d_in[6];
  const float* W2_r = (const float*)d_in[7];
  float* out = (float*)d_out;

  const int N = in_sizes[0] / 128;  // 50000 (packing assumes N <= 65536)
  const int E = in_sizes[1] / 2;
  const int* srcv = edge;
  const int* dstv = edge + E;
  const int NB = (N + (1 << BSHIFT) - 1) >> BSHIFT;  // 782 (<= 1024)

  char* ws = (char*)d_ws;
  size_t off = 0;
  auto alloc = [&](size_t bytes) -> void* {
    void* p = ws + off;
    off += align_up(bytes, 256);
    return p;
  };
  int* rowptr    = (int*)alloc((size_t)(N + 1) * 4);
  int* brow      = (int*)alloc((size_t)(NB + 1) * 4);
  int* blockhist = (int*)alloc((size_t)PB * 1024 * 4);
  unsigned short* col = (unsigned short*)alloc((size_t)E * 2);
  unsigned* stage = (unsigned*)alloc((size_t)E * 4);
  __hip_bfloat16* BT1 = (__hip_bfloat16*)alloc(256 * 256 * 2);
  __hip_bfloat16* BT2 = (__hip_bfloat16*)alloc(256 * 256 * 2);
  __hip_bfloat16* A1  = (__hip_bfloat16*)alloc((size_t)N * 256 * 2);
  __hip_bfloat16* hw2 = (__hip_bfloat16*)alloc((size_t)N * 256 * 2);

  const int conv_blocks = (N * 32 + 255) / 256;
  prep_kernel<<<512 + conv_blocks, 256, 0, stream>>>(x, W1_l, W1_r, W2_l, W2_r,
                                                     BT1, BT2, A1, N * 32);

  const int chunk = (E + PB - 1) / PB;
  bhist_kernel<<<PB, 256, 0, stream>>>(dstv, blockhist, E, chunk);
  scan_all_kernel<<<1, 1024, 0, stream>>>(blockhist, brow, NB);
  bin2_kernel<<<PB, 256, 0, stream>>>(srcv, dstv, brow, blockhist, stage, E, NB, chunk);
  scatter2b_kernel<<<NB, 256, 0, stream>>>(stage, brow, rowptr, col, N, E);

  agg1_kernel<<<N, 64, 0, stream>>>(rowptr, col, A1);

  gemm_fused_kernel<<<(N + 63) / 64, 256, 0, stream>>>(A1, BT1, BT2, b1, hw2, N);

  agg2_kernel<<<N, 64, 0, stream>>>(hw2, rowptr, col, b2, out);
}

// Round 10
// 151.957 us; speedup vs baseline: 1.2596x; 1.0185x over previous
//
#include <hip/hip_runtime.h>
#include <hip/hip_bf16.h>
#include <cstdint>

// ---------------------------------------------------------------------------
// SAGE GNN, 2 layers, N=50000, E=800000, D: 128 -> 256 -> 128.
// 5 kernels:
//   setup:    bhist (blocks 0..PB-1) + bf16^T weights + A1[:,128:256]=bf16(x)
//   bin2:     recompute column-scan+bucket-scan from raw blockhist (parallel,
//             replaces the serial 1-block scan_all), write brow (block 0),
//             bin edges -> bucket-sorted stage (packed 4B)
//   scatter2b: block/bucket, per-node deg+scan in LDS -> rowptr, col(u16)
//   agg1:     A1[:,0:128] = mean_in(bf16 x)   (wave/node, 2 edges/wave,
//             16 rows in flight, shfl_xor(32) merge)
//   gemm_fused: h = relu(A1@W1+b1) -> LDS (swizzled); hw2 = h@[W2l|W2r]
//   agg2:     out = mean_in(hw2[:,:128]) + hw2[:,128:] + b2
// ---------------------------------------------------------------------------

static inline size_t align_up(size_t x, size_t a) { return (x + a - 1) & ~(a - 1); }

using short8 = __attribute__((ext_vector_type(8))) short;
using f32x4  = __attribute__((ext_vector_type(4))) float;

#define BSHIFT 6   // 64 nodes per bucket; NB = ceil(N/64) = 782 (<= 1024)
#define PB 98      // partition blocks for hist/bin

__device__ __forceinline__ float bfpair_lo(unsigned int v) {
  union { unsigned int i; float f; } u; u.i = v << 16; return u.f;
}
__device__ __forceinline__ float bfpair_hi(unsigned int v) {
  union { unsigned int i; float f; } u; u.i = v & 0xffff0000u; return u.f;
}
__device__ __forceinline__ unsigned short f2bf(float f) {
  union { float f; unsigned int i; } u; u.f = f;
  unsigned int r = u.i + 0x7fffu + ((u.i >> 16) & 1u);
  return (unsigned short)(r >> 16);
}

__device__ __forceinline__ void gload_lds16(const void* g, void* l) {
  __builtin_amdgcn_global_load_lds(
      (const __attribute__((address_space(1))) void*)g,
      (__attribute__((address_space(3))) void*)l, 16, 0, 0);
}

// ------------------- setup: bhist + weights + x convert --------------------
__global__ __launch_bounds__(256) void setup_kernel(
    const int* __restrict__ dst, int* __restrict__ blockhist, int E, int chunk,
    const float* __restrict__ x,
    const float* __restrict__ W1l, const float* __restrict__ W1r,
    const float* __restrict__ W2l, const float* __restrict__ W2r,
    __hip_bfloat16* __restrict__ BT1, __hip_bfloat16* __restrict__ BT2,
    __hip_bfloat16* __restrict__ A1, int total4) {
  __shared__ int h[1024];
  const int bb = blockIdx.x;
  const int t = threadIdx.x;
  if (bb < PB) {  // per-block bucket histogram, plain coalesced row stores
    #pragma unroll
    for (int i = t; i < 1024; i += 256) h[i] = 0;
    __syncthreads();
    const int e0 = bb * chunk;
    int e1 = e0 + chunk; if (e1 > E) e1 = E;
    for (int e = e0 + t; e < e1; e += 256) atomicAdd(&h[dst[e] >> BSHIFT], 1);
    __syncthreads();
    #pragma unroll
    for (int i = t; i < 1024; i += 256) blockhist[bb * 1024 + i] = h[i];
    return;
  }
  const int wb = bb - PB;
  if (wb < 512) {  // weights: BT1[n][k], BT2[n][k]
    int idx = (wb & 255) * 256 + t;
    int n = idx >> 8, k = idx & 255;
    if (wb < 256) {
      float v = (k < 128) ? W1l[k * 256 + n] : W1r[(k - 128) * 256 + n];
      BT1[idx] = __float2bfloat16(v);
    } else {
      float v = (n < 128) ? W2l[k * 128 + n] : W2r[k * 128 + (n - 128)];
      BT2[idx] = __float2bfloat16(v);
    }
    return;
  }
  int idx = (wb - 512) * 256 + t;
  if (idx >= total4) return;
  int i = idx >> 5, j4 = (idx & 31) << 2;
  float4 v = *reinterpret_cast<const float4*>(x + (size_t)i * 128 + j4);
  unsigned p0 = ((unsigned)f2bf(v.y) << 16) | f2bf(v.x);
  unsigned p1 = ((unsigned)f2bf(v.w) << 16) | f2bf(v.z);
  *reinterpret_cast<uint2*>(A1 + (size_t)i * 256 + 128 + j4) = make_uint2(p0, p1);
}

// --------------- bin2: in-kernel scans + bin (replaces scan_all) -----------
__global__ __launch_bounds__(256) void bin2_kernel(const int* __restrict__ src,
                                                   const int* __restrict__ dst,
                                                   const int* __restrict__ blockhist,
                                                   unsigned* __restrict__ stage,
                                                   int* __restrict__ brow,
                                                   int E, int NB, int chunk) {
  __shared__ int tot_lds[1024];
  __shared__ int cur_lds[1024];
  __shared__ int wsum[4];
  const int t = threadIdx.x;
  const int pb = blockIdx.x;

  // column scan: totals per bucket + this block's own prefix (coalesced)
  int run[4] = {0, 0, 0, 0};
  int ownp[4] = {0, 0, 0, 0};
  for (int pb2 = 0; pb2 < PB; ++pb2) {
    #pragma unroll
    for (int j = 0; j < 4; ++j) {
      int v = blockhist[pb2 * 1024 + t + 256 * j];
      if (pb2 == pb) ownp[j] = run[j];
      run[j] += v;
    }
  }
  #pragma unroll
  for (int j = 0; j < 4; ++j) {
    tot_lds[t + 256 * j] = run[j];
    cur_lds[t + 256 * j] = ownp[j];
  }
  __syncthreads();

  // block-wide exclusive scan of 1024 bucket totals
  int4 v = *reinterpret_cast<const int4*>(&tot_lds[t * 4]);
  int tsum = v.x + v.y + v.z + v.w;
  const int lane = t & 63, w = t >> 6;
  int inc = tsum;
  #pragma unroll
  for (int off = 1; off < 64; off <<= 1) {
    int u = __shfl_up(inc, off, 64);
    if (lane >= off) inc += u;
  }
  if (lane == 63) wsum[w] = inc;
  __syncthreads();
  int woff = 0;
  for (int k = 0; k < w; ++k) woff += wsum[k];
  int e0x = woff + inc - tsum;
  int p0 = e0x, p1 = p0 + v.x, p2 = p1 + v.y, p3 = p2 + v.z;
  cur_lds[t * 4 + 0] += p0;
  cur_lds[t * 4 + 1] += p1;
  cur_lds[t * 4 + 2] += p2;
  cur_lds[t * 4 + 3] += p3;
  if (pb == 0) {  // publish brow for scatter2b
    if (t * 4 + 0 < NB) brow[t * 4 + 0] = p0;
    if (t * 4 + 1 < NB) brow[t * 4 + 1] = p1;
    if (t * 4 + 2 < NB) brow[t * 4 + 2] = p2;
    if (t * 4 + 3 < NB) brow[t * 4 + 3] = p3;
    if (t == 255) brow[NB] = p3 + v.w;
  }
  __syncthreads();

  // bin this block's edge chunk via LDS cursors
  const int e0 = pb * chunk;
  const int e1 = min(e0 + chunk, E);
  for (int e = e0 + t; e < e1; e += 256) {
    int d = dst[e];
    int p = atomicAdd(&cur_lds[d >> BSHIFT], 1);
    stage[p] = (unsigned)src[e] | ((unsigned)(d & 63) << 16);
  }
}

// one block per bucket: node-local deg count + scan in LDS -> rowptr, col(u16)
__global__ __launch_bounds__(256) void scatter2b_kernel(const unsigned* __restrict__ stage,
                                                        const int* __restrict__ brow,
                                                        int* __restrict__ rowptr,
                                                        unsigned short* __restrict__ col,
                                                        int N, int E) {
  __shared__ int dcnt[64];
  __shared__ int dbase[64];
  const int b = blockIdx.x;
  const int t = threadIdx.x;
  const int n0 = b << BSHIFT;
  const int lo = brow[b], hi = brow[b + 1];
  if (t < 64) dcnt[t] = 0;
  __syncthreads();
  for (int e = lo + t; e < hi; e += 256) atomicAdd(&dcnt[stage[e] >> 16], 1);
  __syncthreads();
  if (t < 64) {
    int v = dcnt[t];
    int inc = v;
    #pragma unroll
    for (int off = 1; off < 64; off <<= 1) {
      int u = __shfl_up(inc, off, 64);
      if (t >= off) inc += u;
    }
    int excl = lo + inc - v;
    dbase[t] = excl;
    dcnt[t] = 0;  // reuse as cursor
    if (n0 + t < N) rowptr[n0 + t] = excl;
  }
  if (b == 0 && t == 0) rowptr[N] = E;
  __syncthreads();
  for (int e = lo + t; e < hi; e += 256) {
    unsigned pr = stage[e];
    int d = pr >> 16;
    int p = atomicAdd(&dcnt[d], 1);
    col[dbase[d] + p] = (unsigned short)(pr & 0xffffu);
  }
}

// ------------------------------ aggregations -------------------------------
// one wave per node, 2 edges/wave: lanes 0-31 = edge e, lanes 32-63 = e+1;
// each lane loads uint2 (4 bf16 cols). Main loop: 16 edges = 16 rows in
// flight. Tiered 8/4/2/1 tails keep MLP for low-degree nodes. shfl_xor(32)
// merges halves once at the end.

#define AGG_LOAD(TBL, OFFS)                                                    \
  {                                                                            \
    int s = col[eidx];                                                         \
    uint2 vv = *reinterpret_cast<const uint2*>(TBL + (size_t)s * 256 + OFFS + q * 4); \
    a0 += bfpair_lo(vv.x); a1 += bfpair_hi(vv.x);                              \
    a2 += bfpair_lo(vv.y); a3 += bfpair_hi(vv.y);                              \
  }

__global__ __launch_bounds__(64) void agg1_kernel(const int* __restrict__ rowptr,
                                                  const unsigned short* __restrict__ col,
                                                  __hip_bfloat16* __restrict__ A1) {
  const int i = blockIdx.x;
  const int t = threadIdx.x;
  const int half = t >> 5;
  const int q = t & 31;
  const int beg = rowptr[i], end = rowptr[i + 1];
  float a0 = 0.f, a1 = 0.f, a2 = 0.f, a3 = 0.f;
  int e = beg;
  for (; e + 15 < end; e += 16) {
    #pragma unroll
    for (int u = 0; u < 8; ++u) {
      int eidx = e + 2 * u + half;
      AGG_LOAD(A1, 128)
    }
  }
  if (e + 7 < end) {
    #pragma unroll
    for (int u = 0; u < 4; ++u) {
      int eidx = e + 2 * u + half;
      AGG_LOAD(A1, 128)
    }
    e += 8;
  }
  if (e + 3 < end) {
    #pragma unroll
    for (int u = 0; u < 2; ++u) {
      int eidx = e + 2 * u + half;
      AGG_LOAD(A1, 128)
    }
    e += 4;
  }
  if (e + 1 < end) {
    int eidx = e + half;
    AGG_LOAD(A1, 128)
    e += 2;
  }
  if (e < end && half == 0) {
    int eidx = e;
    AGG_LOAD(A1, 128)
  }
  a0 += __shfl_xor(a0, 32, 64);
  a1 += __shfl_xor(a1, 32, 64);
  a2 += __shfl_xor(a2, 32, 64);
  a3 += __shfl_xor(a3, 32, 64);
  const int d = end - beg;
  const float inv = 1.0f / (float)(d > 1 ? d : 1);
  if (half == 0) {
    unsigned p0 = ((unsigned)f2bf(a1 * inv) << 16) | f2bf(a0 * inv);
    unsigned p1 = ((unsigned)f2bf(a3 * inv) << 16) | f2bf(a2 * inv);
    *reinterpret_cast<uint2*>(A1 + (size_t)i * 256 + q * 4) = make_uint2(p0, p1);
  }
}

__global__ __launch_bounds__(64) void agg2_kernel(const __hip_bfloat16* __restrict__ hw2,
                                                  const int* __restrict__ rowptr,
                                                  const unsigned short* __restrict__ col,
                                                  const float* __restrict__ b2,
                                                  float* __restrict__ out) {
  const int i = blockIdx.x;
  const int t = threadIdx.x;
  const int half = t >> 5;
  const int q = t & 31;
  const int beg = rowptr[i], end = rowptr[i + 1];
  float a0 = 0.f, a1 = 0.f, a2 = 0.f, a3 = 0.f;
  int e = beg;
  for (; e + 15 < end; e += 16) {
    #pragma unroll
    for (int u = 0; u < 8; ++u) {
      int eidx = e + 2 * u + half;
      AGG_LOAD(hw2, 0)
    }
  }
  if (e + 7 < end) {
    #pragma unroll
    for (int u = 0; u < 4; ++u) {
      int eidx = e + 2 * u + half;
      AGG_LOAD(hw2, 0)
    }
    e += 8;
  }
  if (e + 3 < end) {
    #pragma unroll
    for (int u = 0; u < 2; ++u) {
      int eidx = e + 2 * u + half;
      AGG_LOAD(hw2, 0)
    }
    e += 4;
  }
  if (e + 1 < end) {
    int eidx = e + half;
    AGG_LOAD(hw2, 0)
    e += 2;
  }
  if (e < end && half == 0) {
    int eidx = e;
    AGG_LOAD(hw2, 0)
  }
  a0 += __shfl_xor(a0, 32, 64);
  a1 += __shfl_xor(a1, 32, 64);
  a2 += __shfl_xor(a2, 32, 64);
  a3 += __shfl_xor(a3, 32, 64);
  const int d = end - beg;
  const float inv = 1.0f / (float)(d > 1 ? d : 1);
  if (half == 0) {
    uint2 sv = *reinterpret_cast<const uint2*>(hw2 + (size_t)i * 256 + 128 + q * 4);
    float4 bb = *reinterpret_cast<const float4*>(b2 + q * 4);
    float4 r;
    r.x = a0 * inv + bfpair_lo(sv.x) + bb.x;
    r.y = a1 * inv + bfpair_hi(sv.x) + bb.y;
    r.z = a2 * inv + bfpair_lo(sv.y) + bb.z;
    r.w = a3 * inv + bfpair_hi(sv.y) + bb.w;
    *reinterpret_cast<float4*>(out + (size_t)i * 128 + q * 4) = r;
  }
}

// --------------------------- FUSED double GEMM -----------------------------
__global__ __launch_bounds__(256) void gemm_fused_kernel(
    const __hip_bfloat16* __restrict__ A1,   // [M][256]
    const __hip_bfloat16* __restrict__ BT1,  // [256][256] = B1^T
    const __hip_bfloat16* __restrict__ BT2,  // [256][256] = B2^T
    const float* __restrict__ b1,            // [256]
    __hip_bfloat16* __restrict__ hw2,        // [M][256]
    int M) {
  __shared__ __hip_bfloat16 As[64 * 32];        // 4 KB
  __shared__ __hip_bfloat16 Bs[256 * 32];       // 16 KB
  __shared__ __hip_bfloat16 hLds[64 * 256];     // 32 KB, swizzled
  const int t = threadIdx.x;
  const int lane = t & 63;
  const int w = t >> 6;
  const int wc = w * 64;
  const int bm = blockIdx.x * 64;

  const int srow4 = lane >> 2;
  const int sbyte = (lane & 3) * 16;
  const int fr = lane & 15;
  const int fbyte = (lane >> 4) * 16;
  const int kslot = lane >> 4;

  f32x4 acc[4][4];
  #pragma unroll
  for (int i = 0; i < 4; ++i)
    #pragma unroll
    for (int j = 0; j < 4; ++j) acc[i][j] = (f32x4)(0.f);

  // phase 1: h = relu(A1 @ BT1^T + b1)
  for (int k0 = 0; k0 < 256; k0 += 32) {
    {
      int gr = bm + w * 16 + srow4;
      if (gr >= M) gr = M - 1;
      gload_lds16((const char*)A1 + (size_t)gr * 512 + k0 * 2 + sbyte,
                  (char*)As + w * 1024);
    }
    #pragma unroll
    for (int q = 0; q < 4; ++q) {
      const int c = w * 4 + q;
      const int row = c * 16 + srow4;
      gload_lds16((const char*)BT1 + (size_t)row * 512 + k0 * 2 + sbyte,
                  (char*)Bs + c * 1024);
    }
    __syncthreads();
    short8 af[4], bf[4];
    #pragma unroll
    for (int i = 0; i < 4; ++i) {
      af[i] = *reinterpret_cast<const short8*>((const char*)As + (fr + i * 16) * 64 + fbyte);
      bf[i] = *reinterpret_cast<const short8*>((const char*)Bs + (wc + fr + i * 16) * 64 + fbyte);
    }
    #pragma unroll
    for (int i = 0; i < 4; ++i)
      #pragma unroll
      for (int j = 0; j < 4; ++j)
        acc[i][j] = __builtin_amdgcn_mfma_f32_16x16x32_bf16(af[i], bf[j], acc[i][j], 0, 0, 0);
    __syncthreads();
  }

  // epilogue 1: bias + relu -> hLds (swizzled)
  {
    const int c0 = wc + fr;
    const int r0 = (lane >> 4) * 4;
    float bj[4];
    #pragma unroll
    for (int j = 0; j < 4; ++j) bj[j] = b1[c0 + j * 16];
    #pragma unroll
    for (int i = 0; i < 4; ++i) {
      #pragma unroll
      for (int j = 0; j < 4; ++j) {
        const int c = c0 + j * 16;
        #pragma unroll
        for (int q = 0; q < 4; ++q) {
          const int r = r0 + i * 16 + q;
          float v = fmaxf(acc[i][j][q] + bj[j], 0.f);
          const int byte = r * 512 + (((c >> 3) ^ (r & 7)) << 4) + ((c & 7) << 1);
          *reinterpret_cast<__hip_bfloat16*>((char*)hLds + byte) = __float2bfloat16(v);
        }
      }
    }
  }

  // phase 2: hw2 = h @ BT2^T
  #pragma unroll
  for (int i = 0; i < 4; ++i)
    #pragma unroll
    for (int j = 0; j < 4; ++j) acc[i][j] = (f32x4)(0.f);

  for (int k0 = 0; k0 < 256; k0 += 32) {
    #pragma unroll
    for (int q = 0; q < 4; ++q) {
      const int c = w * 4 + q;
      const int row = c * 16 + srow4;
      gload_lds16((const char*)BT2 + (size_t)row * 512 + k0 * 2 + sbyte,
                  (char*)Bs + c * 1024);
    }
    __syncthreads();
    short8 af[4], bf[4];
    const int ks = (k0 >> 3) + kslot;
    #pragma unroll
    for (int i = 0; i < 4; ++i) {
      const int ra = fr + i * 16;
      af[i] = *reinterpret_cast<const short8*>(
          (const char*)hLds + ra * 512 + ((ks ^ (ra & 7)) << 4));
      bf[i] = *reinterpret_cast<const short8*>((const char*)Bs + (wc + fr + i * 16) * 64 + fbyte);
    }
    #pragma unroll
    for (int i = 0; i < 4; ++i)
      #pragma unroll
      for (int j = 0; j < 4; ++j)
        acc[i][j] = __builtin_amdgcn_mfma_f32_16x16x32_bf16(af[i], bf[j], acc[i][j], 0, 0, 0);
    __syncthreads();
  }

  // epilogue 2
  {
    const int c0 = wc + fr;
    const int r0 = (lane >> 4) * 4;
    #pragma unroll
    for (int i = 0; i < 4; ++i) {
      #pragma unroll
      for (int q = 0; q < 4; ++q) {
        const int r = bm + r0 + i * 16 + q;
        if (r < M) {
          #pragma unroll
          for (int j = 0; j < 4; ++j)
            hw2[(size_t)r * 256 + c0 + j * 16] = __float2bfloat16(acc[i][j][q]);
        }
      }
    }
  }
}

// ------------------------------ launcher -----------------------------------

extern "C" void kernel_launch(void* const* d_in, const int* in_sizes, int n_in,
                              void* d_out, int out_size, void* d_ws, size_t ws_size,
                              hipStream_t stream) {
  const float* x    = (const float*)d_in[0];
  const int*   edge = (const int*)d_in[1];
  const float* W1_l = (const float*)d_in[2];
  const float* b1   = (const float*)d_in[3];
  const float* W1_r = (const float*)d_in[4];
  const float* W2_l = (const float*)d_in[5];
  const float* b2   = (const float*)d_in[6];
  const float* W2_r = (const float*)d_in[7];
  float* out = (float*)d_out;

  const int N = in_sizes[0] / 128;  // 50000 (packing assumes N <= 65536)
  const int E = in_sizes[1] / 2;
  const int* srcv = edge;
  const int* dstv = edge + E;
  const int NB = (N + (1 << BSHIFT) - 1) >> BSHIFT;  // 782 (<= 1024)

  char* ws = (char*)d_ws;
  size_t off = 0;
  auto alloc = [&](size_t bytes) -> void* {
    void* p = ws + off;
    off += align_up(bytes, 256);
    return p;
  };
  int* rowptr    = (int*)alloc((size_t)(N + 1) * 4);
  int* brow      = (int*)alloc((size_t)(NB + 1) * 4);
  int* blockhist = (int*)alloc((size_t)PB * 1024 * 4);
  unsigned short* col = (unsigned short*)alloc((size_t)E * 2);
  unsigned* stage = (unsigned*)alloc((size_t)E * 4);
  __hip_bfloat16* BT1 = (__hip_bfloat16*)alloc(256 * 256 * 2);
  __hip_bfloat16* BT2 = (__hip_bfloat16*)alloc(256 * 256 * 2);
  __hip_bfloat16* A1  = (__hip_bfloat16*)alloc((size_t)N * 256 * 2);
  __hip_bfloat16* hw2 = (__hip_bfloat16*)alloc((size_t)N * 256 * 2);

  const int chunk = (E + PB - 1) / PB;
  const int conv_blocks = (N * 32 + 255) / 256;
  setup_kernel<<<PB + 512 + conv_blocks, 256, 0, stream>>>(
      dstv, blockhist, E, chunk, x, W1_l, W1_r, W2_l, W2_r, BT1, BT2, A1, N * 32);

  bin2_kernel<<<PB, 256, 0, stream>>>(srcv, dstv, blockhist, stage, brow, E, NB, chunk);
  scatter2b_kernel<<<NB, 256, 0, stream>>>(stage, brow, rowptr, col, N, E);

  agg1_kernel<<<N, 64, 0, stream>>>(rowptr, col, A1);

  gemm_fused_kernel<<<(N + 63) / 64, 256, 0, stream>>>(A1, BT1, BT2, b1, hw2, N);

  agg2_kernel<<<N, 64, 0, stream>>>(hw2, rowptr, col, b2, out);
}

// Round 11
// 133.741 us; speedup vs baseline: 1.4312x; 1.1362x over previous
//
#include <hip/hip_runtime.h>
#include <hip/hip_bf16.h>
#include <cstdint>

// ---------------------------------------------------------------------------
// SAGE GNN, 2 layers, N=50000, E=800000, D: 128 -> 256 -> 128.
// 6 kernels:
//   setup:    bhist rows (blocks 0..PB-1) + bf16^T weights + A1[:,128:256]
//   colscan:  ONE WAVE PER BUCKET: shfl-scan the PB per-block counts
//             (2 gather loads, 64+64 lines in flight) -> prefixes + btot
//   bin2:     own-prefix row + btot (coalesced) + in-block bucket scan ->
//             cursors; bin edges -> bucket-sorted stage; publish brow
//   scatter2b: block/bucket, per-node deg+scan in LDS -> rowptr, col(u16)
//   agg1/agg2: wave/node gathers (2 edges/wave, 16 rows in flight)
//   gemm_fused: h = relu(A1@W1+b1) -> LDS (swizzled); hw2 = h@[W2l|W2r]
// ---------------------------------------------------------------------------

static inline size_t align_up(size_t x, size_t a) { return (x + a - 1) & ~(a - 1); }

using short8 = __attribute__((ext_vector_type(8))) short;
using f32x4  = __attribute__((ext_vector_type(4))) float;

#define BSHIFT 6   // 64 nodes per bucket; NB = ceil(N/64) = 782 (<= 1024)
#define PB 128     // partition blocks for hist/bin (<= 128 for colscan)

__device__ __forceinline__ float bfpair_lo(unsigned int v) {
  union { unsigned int i; float f; } u; u.i = v << 16; return u.f;
}
__device__ __forceinline__ float bfpair_hi(unsigned int v) {
  union { unsigned int i; float f; } u; u.i = v & 0xffff0000u; return u.f;
}
__device__ __forceinline__ unsigned short f2bf(float f) {
  union { float f; unsigned int i; } u; u.f = f;
  unsigned int r = u.i + 0x7fffu + ((u.i >> 16) & 1u);
  return (unsigned short)(r >> 16);
}

__device__ __forceinline__ void gload_lds16(const void* g, void* l) {
  __builtin_amdgcn_global_load_lds(
      (const __attribute__((address_space(1))) void*)g,
      (__attribute__((address_space(3))) void*)l, 16, 0, 0);
}

// ------------------- setup: bhist + weights + x convert --------------------
__global__ __launch_bounds__(256) void setup_kernel(
    const int* __restrict__ dst, int* __restrict__ blockhist, int E, int chunk,
    const float* __restrict__ x,
    const float* __restrict__ W1l, const float* __restrict__ W1r,
    const float* __restrict__ W2l, const float* __restrict__ W2r,
    __hip_bfloat16* __restrict__ BT1, __hip_bfloat16* __restrict__ BT2,
    __hip_bfloat16* __restrict__ A1, int total4) {
  __shared__ int h[1024];
  const int bb = blockIdx.x;
  const int t = threadIdx.x;
  if (bb < PB) {  // per-block bucket histogram, plain coalesced row stores
    #pragma unroll
    for (int i = t; i < 1024; i += 256) h[i] = 0;
    __syncthreads();
    const int e0 = bb * chunk;
    int e1 = e0 + chunk; if (e1 > E) e1 = E;
    for (int e = e0 + t; e < e1; e += 256) atomicAdd(&h[dst[e] >> BSHIFT], 1);
    __syncthreads();
    #pragma unroll
    for (int i = t; i < 1024; i += 256) blockhist[bb * 1024 + i] = h[i];
    return;
  }
  const int wb = bb - PB;
  if (wb < 512) {  // weights: BT1[n][k], BT2[n][k]
    int idx = (wb & 255) * 256 + t;
    int n = idx >> 8, k = idx & 255;
    if (wb < 256) {
      float v = (k < 128) ? W1l[k * 256 + n] : W1r[(k - 128) * 256 + n];
      BT1[idx] = __float2bfloat16(v);
    } else {
      float v = (n < 128) ? W2l[k * 128 + n] : W2r[k * 128 + (n - 128)];
      BT2[idx] = __float2bfloat16(v);
    }
    return;
  }
  int idx = (wb - 512) * 256 + t;
  if (idx >= total4) return;
  int i = idx >> 5, j4 = (idx & 31) << 2;
  float4 v = *reinterpret_cast<const float4*>(x + (size_t)i * 128 + j4);
  unsigned p0 = ((unsigned)f2bf(v.y) << 16) | f2bf(v.x);
  unsigned p1 = ((unsigned)f2bf(v.w) << 16) | f2bf(v.z);
  *reinterpret_cast<uint2*>(A1 + (size_t)i * 256 + 128 + j4) = make_uint2(p0, p1);
}

// ---------- colscan: one wave per bucket, shfl-scan over PB blocks ---------
// lane l holds blockhist[l][i] and blockhist[64+l][i]; inclusive shfl scans;
// write back exclusive per-block prefixes in place; btot[i] = column total.
__global__ __launch_bounds__(256) void colscan_kernel(int* __restrict__ blockhist,
                                                      int* __restrict__ btot) {
  const int t = threadIdx.x;
  const int lane = t & 63;
  const int i = blockIdx.x * 4 + (t >> 6);  // bucket id, grid = 256 blocks
  int v0 = blockhist[lane * 1024 + i];
  int v1 = (64 + lane < PB) ? blockhist[(64 + lane) * 1024 + i] : 0;
  int s0 = v0, s1 = v1;
  #pragma unroll
  for (int off = 1; off < 64; off <<= 1) {
    int u0 = __shfl_up(s0, off, 64);
    int u1 = __shfl_up(s1, off, 64);
    if (lane >= off) { s0 += u0; s1 += u1; }
  }
  const int total0 = __shfl(s0, 63, 64);
  const int total1 = __shfl(s1, 63, 64);
  blockhist[lane * 1024 + i] = s0 - v0;
  if (64 + lane < PB) blockhist[(64 + lane) * 1024 + i] = total0 + s1 - v1;
  if (lane == 0) btot[i] = total0 + total1;
}

// --------------- bin2: bucket-base scan + bin (all coalesced) --------------
__global__ __launch_bounds__(256) void bin2_kernel(const int* __restrict__ src,
                                                   const int* __restrict__ dst,
                                                   const int* __restrict__ blockhist,
                                                   const int* __restrict__ btot,
                                                   unsigned* __restrict__ stage,
                                                   int* __restrict__ brow,
                                                   int E, int NB, int chunk) {
  __shared__ int cur_lds[1024];
  __shared__ int wsum[4];
  const int t = threadIdx.x;
  const int pb = blockIdx.x;

  // block-wide exclusive scan of the 1024 bucket totals
  int4 v = *reinterpret_cast<const int4*>(btot + t * 4);
  int tsum = v.x + v.y + v.z + v.w;
  const int lane = t & 63, w = t >> 6;
  int inc = tsum;
  #pragma unroll
  for (int off = 1; off < 64; off <<= 1) {
    int u = __shfl_up(inc, off, 64);
    if (lane >= off) inc += u;
  }
  if (lane == 63) wsum[w] = inc;
  __syncthreads();
  int woff = 0;
  for (int k = 0; k < w; ++k) woff += wsum[k];
  int e0x = woff + inc - tsum;
  int p0 = e0x, p1 = p0 + v.x, p2 = p1 + v.y, p3 = p2 + v.z;

  // cursors = bucket base + this block's own prefix (coalesced int4 row read)
  int4 o = *reinterpret_cast<const int4*>(blockhist + pb * 1024 + t * 4);
  cur_lds[t * 4 + 0] = p0 + o.x;
  cur_lds[t * 4 + 1] = p1 + o.y;
  cur_lds[t * 4 + 2] = p2 + o.z;
  cur_lds[t * 4 + 3] = p3 + o.w;
  if (pb == 0) {  // publish brow for scatter2b
    if (t * 4 + 0 < NB) brow[t * 4 + 0] = p0;
    if (t * 4 + 1 < NB) brow[t * 4 + 1] = p1;
    if (t * 4 + 2 < NB) brow[t * 4 + 2] = p2;
    if (t * 4 + 3 < NB) brow[t * 4 + 3] = p3;
    if (t == 255) brow[NB] = p3 + v.w;
  }
  __syncthreads();

  // bin this block's edge chunk via LDS cursors
  const int e0 = pb * chunk;
  const int e1 = min(e0 + chunk, E);
  for (int e = e0 + t; e < e1; e += 256) {
    int d = dst[e];
    int p = atomicAdd(&cur_lds[d >> BSHIFT], 1);
    stage[p] = (unsigned)src[e] | ((unsigned)(d & 63) << 16);
  }
}

// one block per bucket: node-local deg count + scan in LDS -> rowptr, col(u16)
__global__ __launch_bounds__(256) void scatter2b_kernel(const unsigned* __restrict__ stage,
                                                        const int* __restrict__ brow,
                                                        int* __restrict__ rowptr,
                                                        unsigned short* __restrict__ col,
                                                        int N, int E) {
  __shared__ int dcnt[64];
  __shared__ int dbase[64];
  const int b = blockIdx.x;
  const int t = threadIdx.x;
  const int n0 = b << BSHIFT;
  const int lo = brow[b], hi = brow[b + 1];
  if (t < 64) dcnt[t] = 0;
  __syncthreads();
  for (int e = lo + t; e < hi; e += 256) atomicAdd(&dcnt[stage[e] >> 16], 1);
  __syncthreads();
  if (t < 64) {
    int v = dcnt[t];
    int inc = v;
    #pragma unroll
    for (int off = 1; off < 64; off <<= 1) {
      int u = __shfl_up(inc, off, 64);
      if (t >= off) inc += u;
    }
    int excl = lo + inc - v;
    dbase[t] = excl;
    dcnt[t] = 0;  // reuse as cursor
    if (n0 + t < N) rowptr[n0 + t] = excl;
  }
  if (b == 0 && t == 0) rowptr[N] = E;
  __syncthreads();
  for (int e = lo + t; e < hi; e += 256) {
    unsigned pr = stage[e];
    int d = pr >> 16;
    int p = atomicAdd(&dcnt[d], 1);
    col[dbase[d] + p] = (unsigned short)(pr & 0xffffu);
  }
}

// ------------------------------ aggregations -------------------------------
// one wave per node, 2 edges/wave: lanes 0-31 = edge e, lanes 32-63 = e+1;
// each lane loads uint2 (4 bf16 cols). Main loop: 16 edges = 16 rows in
// flight. Tiered 8/4/2/1 tails keep MLP for low-degree nodes.

#define AGG_LOAD(TBL, OFFS)                                                    \
  {                                                                            \
    int s = col[eidx];                                                         \
    uint2 vv = *reinterpret_cast<const uint2*>(TBL + (size_t)s * 256 + OFFS + q * 4); \
    a0 += bfpair_lo(vv.x); a1 += bfpair_hi(vv.x);                              \
    a2 += bfpair_lo(vv.y); a3 += bfpair_hi(vv.y);                              \
  }

__global__ __launch_bounds__(64) void agg1_kernel(const int* __restrict__ rowptr,
                                                  const unsigned short* __restrict__ col,
                                                  __hip_bfloat16* __restrict__ A1) {
  const int i = blockIdx.x;
  const int t = threadIdx.x;
  const int half = t >> 5;
  const int q = t & 31;
  const int beg = rowptr[i], end = rowptr[i + 1];
  float a0 = 0.f, a1 = 0.f, a2 = 0.f, a3 = 0.f;
  int e = beg;
  for (; e + 15 < end; e += 16) {
    #pragma unroll
    for (int u = 0; u < 8; ++u) {
      int eidx = e + 2 * u + half;
      AGG_LOAD(A1, 128)
    }
  }
  if (e + 7 < end) {
    #pragma unroll
    for (int u = 0; u < 4; ++u) {
      int eidx = e + 2 * u + half;
      AGG_LOAD(A1, 128)
    }
    e += 8;
  }
  if (e + 3 < end) {
    #pragma unroll
    for (int u = 0; u < 2; ++u) {
      int eidx = e + 2 * u + half;
      AGG_LOAD(A1, 128)
    }
    e += 4;
  }
  if (e + 1 < end) {
    int eidx = e + half;
    AGG_LOAD(A1, 128)
    e += 2;
  }
  if (e < end && half == 0) {
    int eidx = e;
    AGG_LOAD(A1, 128)
  }
  a0 += __shfl_xor(a0, 32, 64);
  a1 += __shfl_xor(a1, 32, 64);
  a2 += __shfl_xor(a2, 32, 64);
  a3 += __shfl_xor(a3, 32, 64);
  const int d = end - beg;
  const float inv = 1.0f / (float)(d > 1 ? d : 1);
  if (half == 0) {
    unsigned p0 = ((unsigned)f2bf(a1 * inv) << 16) | f2bf(a0 * inv);
    unsigned p1 = ((unsigned)f2bf(a3 * inv) << 16) | f2bf(a2 * inv);
    *reinterpret_cast<uint2*>(A1 + (size_t)i * 256 + q * 4) = make_uint2(p0, p1);
  }
}

__global__ __launch_bounds__(64) void agg2_kernel(const __hip_bfloat16* __restrict__ hw2,
                                                  const int* __restrict__ rowptr,
                                                  const unsigned short* __restrict__ col,
                                                  const float* __restrict__ b2,
                                                  float* __restrict__ out) {
  const int i = blockIdx.x;
  const int t = threadIdx.x;
  const int half = t >> 5;
  const int q = t & 31;
  const int beg = rowptr[i], end = rowptr[i + 1];
  float a0 = 0.f, a1 = 0.f, a2 = 0.f, a3 = 0.f;
  int e = beg;
  for (; e + 15 < end; e += 16) {
    #pragma unroll
    for (int u = 0; u < 8; ++u) {
      int eidx = e + 2 * u + half;
      AGG_LOAD(hw2, 0)
    }
  }
  if (e + 7 < end) {
    #pragma unroll
    for (int u = 0; u < 4; ++u) {
      int eidx = e + 2 * u + half;
      AGG_LOAD(hw2, 0)
    }
    e += 8;
  }
  if (e + 3 < end) {
    #pragma unroll
    for (int u = 0; u < 2; ++u) {
      int eidx = e + 2 * u + half;
      AGG_LOAD(hw2, 0)
    }
    e += 4;
  }
  if (e + 1 < end) {
    int eidx = e + half;
    AGG_LOAD(hw2, 0)
    e += 2;
  }
  if (e < end && half == 0) {
    int eidx = e;
    AGG_LOAD(hw2, 0)
  }
  a0 += __shfl_xor(a0, 32, 64);
  a1 += __shfl_xor(a1, 32, 64);
  a2 += __shfl_xor(a2, 32, 64);
  a3 += __shfl_xor(a3, 32, 64);
  const int d = end - beg;
  const float inv = 1.0f / (float)(d > 1 ? d : 1);
  if (half == 0) {
    uint2 sv = *reinterpret_cast<const uint2*>(hw2 + (size_t)i * 256 + 128 + q * 4);
    float4 bb = *reinterpret_cast<const float4*>(b2 + q * 4);
    float4 r;
    r.x = a0 * inv + bfpair_lo(sv.x) + bb.x;
    r.y = a1 * inv + bfpair_hi(sv.x) + bb.y;
    r.z = a2 * inv + bfpair_lo(sv.y) + bb.z;
    r.w = a3 * inv + bfpair_hi(sv.y) + bb.w;
    *reinterpret_cast<float4*>(out + (size_t)i * 128 + q * 4) = r;
  }
}

// --------------------------- FUSED double GEMM -----------------------------
__global__ __launch_bounds__(256) void gemm_fused_kernel(
    const __hip_bfloat16* __restrict__ A1,   // [M][256]
    const __hip_bfloat16* __restrict__ BT1,  // [256][256] = B1^T
    const __hip_bfloat16* __restrict__ BT2,  // [256][256] = B2^T
    const float* __restrict__ b1,            // [256]
    __hip_bfloat16* __restrict__ hw2,        // [M][256]
    int M) {
  __shared__ __hip_bfloat16 As[64 * 32];        // 4 KB
  __shared__ __hip_bfloat16 Bs[256 * 32];       // 16 KB
  __shared__ __hip_bfloat16 hLds[64 * 256];     // 32 KB, swizzled
  const int t = threadIdx.x;
  const int lane = t & 63;
  const int w = t >> 6;
  const int wc = w * 64;
  const int bm = blockIdx.x * 64;

  const int srow4 = lane >> 2;
  const int sbyte = (lane & 3) * 16;
  const int fr = lane & 15;
  const int fbyte = (lane >> 4) * 16;
  const int kslot = lane >> 4;

  f32x4 acc[4][4];
  #pragma unroll
  for (int i = 0; i < 4; ++i)
    #pragma unroll
    for (int j = 0; j < 4; ++j) acc[i][j] = (f32x4)(0.f);

  // phase 1: h = relu(A1 @ BT1^T + b1)
  for (int k0 = 0; k0 < 256; k0 += 32) {
    {
      int gr = bm + w * 16 + srow4;
      if (gr >= M) gr = M - 1;
      gload_lds16((const char*)A1 + (size_t)gr * 512 + k0 * 2 + sbyte,
                  (char*)As + w * 1024);
    }
    #pragma unroll
    for (int q = 0; q < 4; ++q) {
      const int c = w * 4 + q;
      const int row = c * 16 + srow4;
      gload_lds16((const char*)BT1 + (size_t)row * 512 + k0 * 2 + sbyte,
                  (char*)Bs + c * 1024);
    }
    __syncthreads();
    short8 af[4], bf[4];
    #pragma unroll
    for (int i = 0; i < 4; ++i) {
      af[i] = *reinterpret_cast<const short8*>((const char*)As + (fr + i * 16) * 64 + fbyte);
      bf[i] = *reinterpret_cast<const short8*>((const char*)Bs + (wc + fr + i * 16) * 64 + fbyte);
    }
    #pragma unroll
    for (int i = 0; i < 4; ++i)
      #pragma unroll
      for (int j = 0; j < 4; ++j)
        acc[i][j] = __builtin_amdgcn_mfma_f32_16x16x32_bf16(af[i], bf[j], acc[i][j], 0, 0, 0);
    __syncthreads();
  }

  // epilogue 1: bias + relu -> hLds (swizzled)
  {
    const int c0 = wc + fr;
    const int r0 = (lane >> 4) * 4;
    float bj[4];
    #pragma unroll
    for (int j = 0; j < 4; ++j) bj[j] = b1[c0 + j * 16];
    #pragma unroll
    for (int i = 0; i < 4; ++i) {
      #pragma unroll
      for (int j = 0; j < 4; ++j) {
        const int c = c0 + j * 16;
        #pragma unroll
        for (int q = 0; q < 4; ++q) {
          const int r = r0 + i * 16 + q;
          float v = fmaxf(acc[i][j][q] + bj[j], 0.f);
          const int byte = r * 512 + (((c >> 3) ^ (r & 7)) << 4) + ((c & 7) << 1);
          *reinterpret_cast<__hip_bfloat16*>((char*)hLds + byte) = __float2bfloat16(v);
        }
      }
    }
  }

  // phase 2: hw2 = h @ BT2^T
  #pragma unroll
  for (int i = 0; i < 4; ++i)
    #pragma unroll
    for (int j = 0; j < 4; ++j) acc[i][j] = (f32x4)(0.f);

  for (int k0 = 0; k0 < 256; k0 += 32) {
    #pragma unroll
    for (int q = 0; q < 4; ++q) {
      const int c = w * 4 + q;
      const int row = c * 16 + srow4;
      gload_lds16((const char*)BT2 + (size_t)row * 512 + k0 * 2 + sbyte,
                  (char*)Bs + c * 1024);
    }
    __syncthreads();
    short8 af[4], bf[4];
    const int ks = (k0 >> 3) + kslot;
    #pragma unroll
    for (int i = 0; i < 4; ++i) {
      const int ra = fr + i * 16;
      af[i] = *reinterpret_cast<const short8*>(
          (const char*)hLds + ra * 512 + ((ks ^ (ra & 7)) << 4));
      bf[i] = *reinterpret_cast<const short8*>((const char*)Bs + (wc + fr + i * 16) * 64 + fbyte);
    }
    #pragma unroll
    for (int i = 0; i < 4; ++i)
      #pragma unroll
      for (int j = 0; j < 4; ++j)
        acc[i][j] = __builtin_amdgcn_mfma_f32_16x16x32_bf16(af[i], bf[j], acc[i][j], 0, 0, 0);
    __syncthreads();
  }

  // epilogue 2
  {
    const int c0 = wc + fr;
    const int r0 = (lane >> 4) * 4;
    #pragma unroll
    for (int i = 0; i < 4; ++i) {
      #pragma unroll
      for (int q = 0; q < 4; ++q) {
        const int r = bm + r0 + i * 16 + q;
        if (r < M) {
          #pragma unroll
          for (int j = 0; j < 4; ++j)
            hw2[(size_t)r * 256 + c0 + j * 16] = __float2bfloat16(acc[i][j][q]);
        }
      }
    }
  }
}

// ------------------------------ launcher -----------------------------------

extern "C" void kernel_launch(void* const* d_in, const int* in_sizes, int n_in,
                              void* d_out, int out_size, void* d_ws, size_t ws_size,
                              hipStream_t stream) {
  const float* x    = (const float*)d_in[0];
  const int*   edge = (const int*)d_in[1];
  const float* W1_l = (const float*)d_in[2];
  const float* b1   = (const float*)d_in[3];
  const float* W1_r = (const float*)d_in[4];
  const float* W2_l = (const float*)d_in[5];
  const float* b2   = (const float*)d_in[6];
  const float* W2_r = (const float*)d_in[7];
  float* out = (float*)d_out;

  const int N = in_sizes[0] / 128;  // 50000 (packing assumes N <= 65536)
  const int E = in_sizes[1] / 2;
  const int* srcv = edge;
  const int* dstv = edge + E;
  const int NB = (N + (1 << BSHIFT) - 1) >> BSHIFT;  // 782 (<= 1024)

  char* ws = (char*)d_ws;
  size_t off = 0;
  auto alloc = [&](size_t bytes) -> void* {
    void* p = ws + off;
    off += align_up(bytes, 256);
    return p;
  };
  int* rowptr    = (int*)alloc((size_t)(N + 1) * 4);
  int* brow      = (int*)alloc((size_t)(NB + 1) * 4);
  int* btot      = (int*)alloc(1024 * 4);
  int* blockhist = (int*)alloc((size_t)PB * 1024 * 4);
  unsigned short* col = (unsigned short*)alloc((size_t)E * 2);
  unsigned* stage = (unsigned*)alloc((size_t)E * 4);
  __hip_bfloat16* BT1 = (__hip_bfloat16*)alloc(256 * 256 * 2);
  __hip_bfloat16* BT2 = (__hip_bfloat16*)alloc(256 * 256 * 2);
  __hip_bfloat16* A1  = (__hip_bfloat16*)alloc((size_t)N * 256 * 2);
  __hip_bfloat16* hw2 = (__hip_bfloat16*)alloc((size_t)N * 256 * 2);

  const int chunk = (E + PB - 1) / PB;
  const int conv_blocks = (N * 32 + 255) / 256;
  setup_kernel<<<PB + 512 + conv_blocks, 256, 0, stream>>>(
      dstv, blockhist, E, chunk, x, W1_l, W1_r, W2_l, W2_r, BT1, BT2, A1, N * 32);

  colscan_kernel<<<256, 256, 0, stream>>>(blockhist, btot);
  bin2_kernel<<<PB, 256, 0, stream>>>(srcv, dstv, blockhist, btot, stage, brow, E, NB, chunk);
  scatter2b_kernel<<<NB, 256, 0, stream>>>(stage, brow, rowptr, col, N, E);

  agg1_kernel<<<N, 64, 0, stream>>>(rowptr, col, A1);

  gemm_fused_kernel<<<(N + 63) / 64, 256, 0, stream>>>(A1, BT1, BT2, b1, hw2, N);

  agg2_kernel<<<N, 64, 0, stream>>>(hw2, rowptr, col, b2, out);
}